// Round 1
// 700.905 us; speedup vs baseline: 1.3756x; 1.3756x over previous
//
#include <hip/hip_runtime.h>

// IJGNN attention-MPNN, 3 iterations. fp32 in/out, bf16 internal.
// Edges processed in dst-sorted (CSR) order; edge head scatters back via eid.
// This rev: vectorized epilogues via in-LDS transpose (f32 for edge partials --
// no extra rounding). Epilogue gathers/stores are 16B vector ops instead of
// per-element u16 scalar ops (was 128 scalar loads + 64 scalar stores/thread).

#define GN 25000
#define GE 400000
#define NODE_BLKS 196   // ceil(GN/128)
#define EDGE_BLKS 3125  // GE/128 exact

typedef unsigned short u16;
typedef __attribute__((ext_vector_type(8))) short bf16x8;
typedef __attribute__((ext_vector_type(4))) float f32x4;

__device__ inline float b2f(u16 v) {
  union { unsigned int u; float f; } x; x.u = ((unsigned int)v) << 16; return x.f;
}
__device__ inline u16 f2b(float f) {
  union { float f; unsigned int u; } x; x.f = f;
  unsigned int u = x.u;
  u += 0x7fffu + ((u >> 16) & 1u);
  return (u16)(u >> 16);
}

// ---------------- dtype probe + convert ----------------
__global__ void detect_dtype(const void* nf, int* flag) {
  if (blockIdx.x == 0 && threadIdx.x == 0) {
    const u16* p = (const u16*)nf;
    int cnt = 0;
    for (int i = 0; i < 512; i += 2) {
      int e = (p[i] >> 7) & 0xFF;
      if (e >= 0x70 && e <= 0x85) cnt++;
    }
    *flag = (cnt < 128) ? 1 : 0;
  }
}

__global__ void convert_kernel(const void* src, u16* dst, long n, const int* flag) {
  int f32 = *flag;
  long i = (long)blockIdx.x * blockDim.x + threadIdx.x;
  long stride = (long)gridDim.x * blockDim.x;
  for (; i < n; i += stride)
    dst[i] = f32 ? f2b(((const float*)src)[i]) : ((const u16*)src)[i];
}

// gather ef rows into dst-sorted order (+convert)
__global__ void gather_ef(const void* ef, const int* eid, u16* efc, const int* flag) {
  int f32 = *flag;
  long idx = (long)blockIdx.x * blockDim.x + threadIdx.x;
  long stride = (long)gridDim.x * blockDim.x;
  long ntot = (long)GE * 32;
  for (; idx < ntot; idx += stride) {
    long j = idx >> 5;
    int c = (int)(idx & 31);
    long e = eid[j];
    efc[idx] = f32 ? f2b(((const float*)ef)[e * 32 + c]) : ((const u16*)ef)[e * 32 + c];
  }
}

__global__ void gather_meta(const int* src, const int* dst, const int* eid,
                            int* srcs, int* dsts, int n) {
  int j = blockIdx.x * blockDim.x + threadIdx.x;
  if (j < n) { int e = eid[j]; srcs[j] = src[e]; dsts[j] = dst[e]; }
}

// ---------------- weight pre-transpose ----------------
__global__ void prep_weights(const u16* We, const u16* Wn, const u16* Won, const u16* Woe,
                             u16* WeT, u16* WnpT, u16* WnuT, u16* WoN, u16* WoE) {
  int tid = blockIdx.x * blockDim.x + threadIdx.x;
  int nt = gridDim.x * blockDim.x;
  for (int i = tid; i < 128 * 160; i += nt) { int n = i / 160, k = i % 160; WeT[i] = We[(320 + k) * 128 + n]; }
  for (int i = tid; i < 256 * 160; i += nt) {
    int c = i / 160, k = i % 160;
    WnpT[i] = (c < 128) ? We[k * 128 + c] : We[(160 + k) * 128 + (c - 128)];
  }
  for (int i = tid; i < 128 * 288; i += nt) { int c = i / 288, k = i % 288; WnuT[i] = Wn[k * 128 + c]; }
  for (int i = tid; i < 32 * 128; i += nt) {
    int c = i / 128, k = i % 128;
    WoN[i] = Won[k * 32 + c];
    WoE[i] = Woe[k * 32 + c];
  }
}

// ---------------- CSR build ----------------
__global__ void hist_kernel(const int* dst, int* counts, int n) {
  for (int e = blockIdx.x * blockDim.x + threadIdx.x; e < n; e += gridDim.x * blockDim.x)
    atomicAdd(&counts[dst[e]], 1);
}

__global__ __launch_bounds__(256) void scan_kernel(int* cursor, int* rowptr, int n) {
  __shared__ int part[256];
  int t = threadIdx.x;
  int per = (n + 255) / 256;
  int lo = t * per;
  int hi = lo + per; if (hi > n) hi = n;
  if (lo > n) lo = n;
  int s = 0;
  for (int i = lo; i < hi; ++i) s += cursor[i];
  part[t] = s;
  __syncthreads();
  for (int off = 1; off < 256; off <<= 1) {
    int v = (t >= off) ? part[t - off] : 0;
    __syncthreads();
    part[t] += v;
    __syncthreads();
  }
  int run = (t > 0) ? part[t - 1] : 0;
  for (int i = lo; i < hi; ++i) {
    int c = cursor[i];
    cursor[i] = run;
    rowptr[i + 1] = run + c;
    run += c;
  }
  if (t == 0) rowptr[0] = 0;
}

__global__ void fill_kernel(const int* dst, int* cursor, int* eid, int n) {
  for (int e = blockIdx.x * blockDim.x + threadIdx.x; e < n; e += gridDim.x * blockDim.x) {
    int p = atomicAdd(&cursor[dst[e]], 1);
    eid[p] = e;
  }
}

// ---------------- node projections (MFMA): Xs/Xd [N,128] bf16, as/ad [N] fp32 ----------------
__global__ __launch_bounds__(256)
void node_proj(const u16* HNF, const u16* nf, const u16* WnpT, const u16* W_attn,
               u16* Xs, u16* Xd, float* as_, float* ad_, int kc0, int nrows) {
  __shared__ union {
    struct { __align__(16) u16 A[128][40]; __align__(16) u16 B[128][40]; } st;
    u16 C[128][130];  // bf16 transpose buffer (final values; no extra rounding)
  } sm;
  __shared__ float dotbuf[128][2];
  int sel = blockIdx.y, blk = blockIdx.x, tid = threadIdx.x;
  int lane = tid & 63, wv = tid >> 6, wr = wv & 1, wc = wv >> 1;
  const u16* BT = WnpT + sel * 128 * 160;
  u16* OUT = sel ? Xd : Xs;
  float* AOUT = sel ? ad_ : as_;
  const u16* wa = W_attn + sel * 160;
  f32x4 acc[4][4];
  f32x4 zf = {0.f, 0.f, 0.f, 0.f};
  for (int i = 0; i < 4; ++i) for (int j = 0; j < 4; ++j) acc[i][j] = zf;
  float dp = 0.f;
  int arow = tid >> 1, ahalf = (tid & 1) * 16;
  int r0 = blk * 128;
  for (int kc = kc0; kc < 5; ++kc) {
    {
      int r = r0 + arow;
      uint4 v0 = make_uint4(0, 0, 0, 0), v1 = make_uint4(0, 0, 0, 0);
      if (r < nrows) {
        const uint4* p = (kc < 4) ? (const uint4*)(HNF + (size_t)r * 128 + kc * 32 + ahalf)
                                  : (const uint4*)(nf + (size_t)r * 32 + ahalf);
        v0 = p[0]; v1 = p[1];
      }
      *(uint4*)&sm.st.A[arow][ahalf] = v0;
      *(uint4*)&sm.st.A[arow][ahalf + 8] = v1;
    }
    {
      const uint4* p = (const uint4*)(BT + arow * 160 + kc * 32 + ahalf);
      uint4 v0 = p[0], v1 = p[1];
      *(uint4*)&sm.st.B[arow][ahalf] = v0;
      *(uint4*)&sm.st.B[arow][ahalf + 8] = v1;
    }
    __syncthreads();
    {
      float s = 0.f;
      for (int j = 0; j < 16; ++j) s += b2f(sm.st.A[arow][ahalf + j]) * b2f(wa[kc * 32 + ahalf + j]);
      dp += s;
    }
    int q = lane >> 4, l16 = lane & 15;
    bf16x8 af[4], bfr[4];
    for (int i = 0; i < 4; ++i) af[i] = *(const bf16x8*)&sm.st.A[wr * 64 + i * 16 + l16][q * 8];
    for (int j = 0; j < 4; ++j) bfr[j] = *(const bf16x8*)&sm.st.B[wc * 64 + j * 16 + l16][q * 8];
    for (int i = 0; i < 4; ++i)
      for (int j = 0; j < 4; ++j)
        acc[i][j] = __builtin_amdgcn_mfma_f32_16x16x32_bf16(af[i], bfr[j], acc[i][j], 0, 0, 0);
    __syncthreads();
  }
  dotbuf[arow][tid & 1] = dp;
  // scatter acc -> LDS transpose buffer (overlays staging; K-loop is done)
  {
    int q = lane >> 4, l16 = lane & 15;
    for (int i = 0; i < 4; ++i)
      for (int j = 0; j < 4; ++j) {
        int col = wc * 64 + j * 16 + l16;
        for (int rr = 0; rr < 4; ++rr) {
          int row = wr * 64 + i * 16 + q * 4 + rr;
          sm.C[row][col] = f2b(acc[i][j][rr]);
        }
      }
  }
  __syncthreads();
  if (tid < 128) {
    int r = r0 + tid;
    if (r < nrows) AOUT[r] = dotbuf[tid][0] + dotbuf[tid][1];
  }
  // vectorized store: each thread owns one row-half (64 cols = 8x dwordx4)
  {
    int r = tid >> 1, h = (tid & 1) * 64;
    int rg = r0 + r;
    if (rg < nrows) {
      uint4* po = (uint4*)(OUT + (size_t)rg * 128 + h);
      for (int k = 0; k < 8; ++k) {
        unsigned int a0 = *(const unsigned int*)&sm.C[r][h + k * 8];
        unsigned int a1 = *(const unsigned int*)&sm.C[r][h + k * 8 + 2];
        unsigned int a2 = *(const unsigned int*)&sm.C[r][h + k * 8 + 4];
        unsigned int a3 = *(const unsigned int*)&sm.C[r][h + k * 8 + 6];
        po[k] = make_uint4(a0, a1, a2, a3);
      }
    }
  }
}

// ---------------- edge stage (sorted order): MFMA GEMM + fused epilogue ----------------
// Epilogue via two-pass f32 LDS transpose (64 cols/pass): acc+b_edge scattered
// into LDS as f32 (no extra rounding), then each thread handles one row x 32
// cols with vector gathers of Xs/Xd (16B) and vector stores of HEF.
__global__ __launch_bounds__(256, 4)
void edge_fused(u16* HEF, const u16* ef, const u16* WeT, const u16* W_attn,
                const u16* b_edge, const u16* b_attn, const int* srcs, const int* dsts,
                const u16* Xs, const u16* Xd, const float* as_, const float* ad_,
                float* logit, int kc0) {
  __shared__ union {
    struct { __align__(16) u16 A[128][40]; __align__(16) u16 B[128][40]; } st;
    float C[128][65];  // stride 65 dwords: bank=(r+c)%32, 2-way max on reads
  } sm;
  __shared__ float dotbuf[128];
  int blk = blockIdx.x, tid = threadIdx.x;
  int lane = tid & 63, wv = tid >> 6, wr = wv & 1, wc = wv >> 1;
  int q = lane >> 4, l16 = lane & 15;
  f32x4 acc[4][4];
  f32x4 zf = {0.f, 0.f, 0.f, 0.f};
  for (int i = 0; i < 4; ++i) for (int j = 0; j < 4; ++j) acc[i][j] = zf;
  float dp[4] = {0.f, 0.f, 0.f, 0.f};
  int arow = tid >> 1, ahalf = (tid & 1) * 16;
  long e0 = (long)blk * 128;
  const u16* wa = W_attn + 320;
  for (int kc = kc0; kc < 5; ++kc) {
    {
      long e = e0 + arow;
      const uint4* p = (kc < 4) ? (const uint4*)(HEF + e * 128 + kc * 32 + ahalf)
                                : (const uint4*)(ef + e * 32 + ahalf);
      uint4 v0 = p[0], v1 = p[1];
      *(uint4*)&sm.st.A[arow][ahalf] = v0;
      *(uint4*)&sm.st.A[arow][ahalf + 8] = v1;
    }
    {
      const uint4* p = (const uint4*)(WeT + arow * 160 + kc * 32 + ahalf);
      uint4 v0 = p[0], v1 = p[1];
      *(uint4*)&sm.st.B[arow][ahalf] = v0;
      *(uint4*)&sm.st.B[arow][ahalf + 8] = v1;
    }
    __syncthreads();
    bf16x8 af[4], bfr[4];
    for (int i = 0; i < 4; ++i) af[i] = *(const bf16x8*)&sm.st.A[wr * 64 + i * 16 + l16][q * 8];
    for (int j = 0; j < 4; ++j) bfr[j] = *(const bf16x8*)&sm.st.B[wc * 64 + j * 16 + l16][q * 8];
    if (wc == 0) {
      bf16x8 wv8 = *(const bf16x8*)&wa[kc * 32 + q * 8];
      float wf[8];
      for (int j = 0; j < 8; ++j) wf[j] = b2f((u16)wv8[j]);
      for (int i = 0; i < 4; ++i)
        for (int j = 0; j < 8; ++j) dp[i] += b2f((u16)af[i][j]) * wf[j];
    }
    for (int i = 0; i < 4; ++i)
      for (int j = 0; j < 4; ++j)
        acc[i][j] = __builtin_amdgcn_mfma_f32_16x16x32_bf16(af[i], bfr[j], acc[i][j], 0, 0, 0);
    __syncthreads();
  }
  if (wc == 0) {
    for (int i = 0; i < 4; ++i) {
      dp[i] += __shfl_xor(dp[i], 16);
      dp[i] += __shfl_xor(dp[i], 32);
    }
    if (q == 0)
      for (int i = 0; i < 4; ++i) dotbuf[wr * 64 + i * 16 + l16] = dp[i];
  }
  int r = tid >> 1;          // row this thread owns in the vector phase
  int h2 = (tid & 1) * 32;   // col offset within the 64-col pass half
  long e = e0 + r;
  int s = srcs[e], d = dsts[e];
  for (int p = 0; p < 2; ++p) {
    // issue vector gathers early: latency hides under LDS scatter + barrier
    uint4 gvs[4], gvd[4];
    {
      const uint4* ps = (const uint4*)(Xs + (size_t)s * 128 + p * 64 + h2);
      const uint4* pd = (const uint4*)(Xd + (size_t)d * 128 + p * 64 + h2);
      for (int k = 0; k < 4; ++k) { gvs[k] = ps[k]; gvd[k] = pd[k]; }
    }
    if (wc == p) {  // this wave's acc covers cols [p*64, p*64+64)
      for (int i = 0; i < 4; ++i)
        for (int j = 0; j < 4; ++j) {
          int col = j * 16 + l16;
          float bb = b2f(b_edge[p * 64 + col]);
          for (int rr = 0; rr < 4; ++rr) {
            int row = wr * 64 + i * 16 + q * 4 + rr;
            sm.C[row][col] = acc[i][j][rr] + bb;
          }
        }
    }
    __syncthreads();
    if (p == 0 && tid < 128) {
      long ee = e0 + tid;
      logit[ee] = dotbuf[tid] + as_[srcs[ee]] + ad_[dsts[ee]] + b2f(b_attn[0]);
    }
    uint4 o[4];
    for (int k = 0; k < 4; ++k) {
      unsigned int ov[4];
      for (int w = 0; w < 4; ++w) {
        int c = h2 + k * 8 + 2 * w;
        float c0 = sm.C[r][c], c1 = sm.C[r][c + 1];
        unsigned int us = ((const unsigned int*)&gvs[k])[w];
        unsigned int ud = ((const unsigned int*)&gvd[k])[w];
        float v0 = c0 + b2f((u16)(us & 0xffffu)) + b2f((u16)(ud & 0xffffu));
        float v1 = c1 + b2f((u16)(us >> 16)) + b2f((u16)(ud >> 16));
        v0 = fmaxf(v0, 0.f);
        v1 = fmaxf(v1, 0.f);
        ov[w] = (unsigned int)f2b(v0) | ((unsigned int)f2b(v1) << 16);
      }
      o[k] = make_uint4(ov[0], ov[1], ov[2], ov[3]);
    }
    {
      uint4* po = (uint4*)(HEF + e * 128 + p * 64 + h2);
      for (int k = 0; k < 4; ++k) po[k] = o[k];
    }
    if (p == 0) __syncthreads();  // pass-1 scatter must wait for pass-0 reads
  }
}

// ---------------- per-dst softmax + aggregation (sorted M: sequential reads) ----------------
__global__ __launch_bounds__(256)
void aggregate(const int* rowptr, const float* logit, const u16* M, u16* AGG, int nrows) {
  int gw = (blockIdx.x * blockDim.x + threadIdx.x) >> 6;
  int lane = threadIdx.x & 63;
  if (gw >= nrows) return;
  int beg = rowptr[gw], end = rowptr[gw + 1];
  float acc0 = 0.f, acc1 = 0.f;
  if (beg < end) {
    float mx = -1e30f;
    for (int j = beg + lane; j < end; j += 64) mx = fmaxf(mx, logit[j]);
    for (int off = 32; off > 0; off >>= 1) mx = fmaxf(mx, __shfl_xor(mx, off));
    float denom = 0.f;
    for (int j = beg; j < end; ++j) {
      float w = __expf(logit[j] - mx);
      denom += w;
      unsigned int mm = *(const unsigned int*)(M + (size_t)j * 128 + 2 * lane);
      acc0 += w * b2f((u16)(mm & 0xffffu));
      acc1 += w * b2f((u16)(mm >> 16));
    }
    float inv = 1.0f / fmaxf(denom, 1e-16f);
    acc0 *= inv; acc1 *= inv;
  }
  unsigned int out = (unsigned int)f2b(acc0) | ((unsigned int)f2b(acc1) << 16);
  *(unsigned int*)(AGG + (size_t)gw * 128 + 2 * lane) = out;
}

// ---------------- node update (MFMA, in-place HNF) ----------------
__global__ __launch_bounds__(256)
void node_update(u16* HNF, const u16* nf, const u16* AGG, const u16* WnuT,
                 const u16* b_node, int kc0, int nrows) {
  __shared__ union {
    struct { __align__(16) u16 A[128][40]; __align__(16) u16 B[128][40]; } st;
    u16 C[128][130];
  } sm;
  int blk = blockIdx.x, tid = threadIdx.x;
  int lane = tid & 63, wv = tid >> 6, wr = wv & 1, wc = wv >> 1;
  f32x4 acc[4][4];
  f32x4 zf = {0.f, 0.f, 0.f, 0.f};
  for (int i = 0; i < 4; ++i) for (int j = 0; j < 4; ++j) acc[i][j] = zf;
  int arow = tid >> 1, ahalf = (tid & 1) * 16;
  int r0 = blk * 128;
  for (int kc = kc0; kc < 9; ++kc) {
    {
      int r = r0 + arow;
      uint4 v0 = make_uint4(0, 0, 0, 0), v1 = make_uint4(0, 0, 0, 0);
      if (r < nrows) {
        const u16* p;
        if (kc < 4) p = HNF + (size_t)r * 128 + kc * 32 + ahalf;
        else if (kc == 4) p = nf + (size_t)r * 32 + ahalf;
        else p = AGG + (size_t)r * 128 + (kc - 5) * 32 + ahalf;
        v0 = ((const uint4*)p)[0];
        v1 = ((const uint4*)p)[1];
      }
      *(uint4*)&sm.st.A[arow][ahalf] = v0;
      *(uint4*)&sm.st.A[arow][ahalf + 8] = v1;
    }
    {
      const uint4* p = (const uint4*)(WnuT + arow * 288 + kc * 32 + ahalf);
      uint4 v0 = p[0], v1 = p[1];
      *(uint4*)&sm.st.B[arow][ahalf] = v0;
      *(uint4*)&sm.st.B[arow][ahalf + 8] = v1;
    }
    __syncthreads();
    int q = lane >> 4, l16 = lane & 15;
    bf16x8 af[4], bfr[4];
    for (int i = 0; i < 4; ++i) af[i] = *(const bf16x8*)&sm.st.A[wr * 64 + i * 16 + l16][q * 8];
    for (int j = 0; j < 4; ++j) bfr[j] = *(const bf16x8*)&sm.st.B[wc * 64 + j * 16 + l16][q * 8];
    for (int i = 0; i < 4; ++i)
      for (int j = 0; j < 4; ++j)
        acc[i][j] = __builtin_amdgcn_mfma_f32_16x16x32_bf16(af[i], bfr[j], acc[i][j], 0, 0, 0);
    __syncthreads();
  }
  int q = lane >> 4, l16 = lane & 15;
  for (int i = 0; i < 4; ++i)
    for (int j = 0; j < 4; ++j) {
      int col = wc * 64 + j * 16 + l16;
      float bb = b2f(b_node[col]);
      for (int rr = 0; rr < 4; ++rr) {
        int row = wr * 64 + i * 16 + q * 4 + rr;
        sm.C[row][col] = f2b(fmaxf(acc[i][j][rr] + bb, 0.f));
      }
    }
  __syncthreads();
  {
    int r = tid >> 1, h = (tid & 1) * 64;
    int rg = r0 + r;
    if (rg < nrows) {
      uint4* po = (uint4*)(HNF + (size_t)rg * 128 + h);
      for (int k = 0; k < 8; ++k) {
        unsigned int a0 = *(const unsigned int*)&sm.C[r][h + k * 8];
        unsigned int a1 = *(const unsigned int*)&sm.C[r][h + k * 8 + 2];
        unsigned int a2 = *(const unsigned int*)&sm.C[r][h + k * 8 + 4];
        unsigned int a3 = *(const unsigned int*)&sm.C[r][h + k * 8 + 6];
        po[k] = make_uint4(a0, a1, a2, a3);
      }
    }
  }
}

// ---------------- output heads (MFMA, fp32 output, optional row remap) ----------------
__global__ __launch_bounds__(256)
void head_kernel(const u16* IN, const u16* WT, const u16* bias, float* OUT, long R,
                 const int* remap) {
  __shared__ __align__(16) u16 Asm[128][40];
  __shared__ __align__(16) u16 Bsm[32][40];
  int blk = blockIdx.x, tid = threadIdx.x;
  int lane = tid & 63, wv = tid >> 6;
  f32x4 acc[2][2];
  f32x4 zf = {0.f, 0.f, 0.f, 0.f};
  for (int i = 0; i < 2; ++i) for (int j = 0; j < 2; ++j) acc[i][j] = zf;
  int arow = tid >> 1, ahalf = (tid & 1) * 16;
  long r0 = (long)blk * 128;
  for (int kc = 0; kc < 4; ++kc) {
    {
      long r = r0 + arow;
      uint4 v0 = make_uint4(0, 0, 0, 0), v1 = make_uint4(0, 0, 0, 0);
      if (r < R) {
        const uint4* p = (const uint4*)(IN + r * 128 + kc * 32 + ahalf);
        v0 = p[0]; v1 = p[1];
      }
      *(uint4*)&Asm[arow][ahalf] = v0;
      *(uint4*)&Asm[arow][ahalf + 8] = v1;
    }
    if (tid < 64) {
      const uint4* p = (const uint4*)(WT + arow * 128 + kc * 32 + ahalf);
      uint4 v0 = p[0], v1 = p[1];
      *(uint4*)&Bsm[arow][ahalf] = v0;
      *(uint4*)&Bsm[arow][ahalf + 8] = v1;
    }
    __syncthreads();
    int q = lane >> 4, l16 = lane & 15;
    bf16x8 af[2], bfr[2];
    for (int i = 0; i < 2; ++i) af[i] = *(const bf16x8*)&Asm[wv * 32 + i * 16 + l16][q * 8];
    for (int j = 0; j < 2; ++j) bfr[j] = *(const bf16x8*)&Bsm[j * 16 + l16][q * 8];
    for (int i = 0; i < 2; ++i)
      for (int j = 0; j < 2; ++j)
        acc[i][j] = __builtin_amdgcn_mfma_f32_16x16x32_bf16(af[i], bfr[j], acc[i][j], 0, 0, 0);
    __syncthreads();
  }
  int q = lane >> 4, l16 = lane & 15;
  for (int i = 0; i < 2; ++i)
    for (int rr = 0; rr < 4; ++rr) {
      long r = r0 + wv * 32 + i * 16 + q * 4 + rr;
      if (r < R) {
        long ro = remap ? (long)remap[r] : r;
        for (int j = 0; j < 2; ++j) {
          int col = j * 16 + l16;
          OUT[ro * 32 + col] = acc[i][j][rr] + b2f(bias[col]);
        }
      }
    }
}

extern "C" void kernel_launch(void* const* d_in, const int* in_sizes, int n_in,
                              void* d_out, int out_size, void* d_ws, size_t ws_size,
                              hipStream_t stream) {
  const size_t REQUIRED = 160000000;
  if (ws_size < REQUIRED) return;

  const void* nf_r = d_in[0];
  const void* ef_r = d_in[1];
  const int* src = (const int*)d_in[2];
  const int* dst = (const int*)d_in[3];

  char* ws = (char*)d_ws;
  auto alloc = [&](size_t bytes) {
    char* p = ws;
    ws += (bytes + 255) & ~(size_t)255;
    return p;
  };
  u16* HEF = (u16*)alloc((size_t)GE * 128 * 2);
  u16* HNF = (u16*)alloc((size_t)GN * 128 * 2);
  u16* Xs = (u16*)alloc((size_t)GN * 128 * 2);
  u16* Xd = (u16*)alloc((size_t)GN * 128 * 2);
  float* as_ = (float*)alloc((size_t)GN * 4);
  float* ad_ = (float*)alloc((size_t)GN * 4);
  float* logit = (float*)alloc((size_t)GE * 4);
  int* rowptr = (int*)alloc((size_t)(GN + 1) * 4);
  int* cursor = (int*)alloc((size_t)GN * 4);
  int* eid = (int*)alloc((size_t)GE * 4);
  int* srcs = (int*)alloc((size_t)GE * 4);
  int* dsts = (int*)alloc((size_t)GE * 4);
  u16* WeT = (u16*)alloc(128 * 160 * 2);
  u16* WnpT = (u16*)alloc(256 * 160 * 2);
  u16* WnuT = (u16*)alloc(128 * 288 * 2);
  u16* WoN = (u16*)alloc(32 * 128 * 2);
  u16* WoE = (u16*)alloc(32 * 128 * 2);
  u16* nfc = (u16*)alloc((size_t)GN * 32 * 2);
  u16* efc = (u16*)alloc((size_t)GE * 32 * 2);
  u16* Wec = (u16*)alloc(480 * 128 * 2);
  u16* bec = (u16*)alloc(128 * 2);
  u16* Wac = (u16*)alloc(480 * 2);
  u16* bac = (u16*)alloc(2);
  u16* Wnc = (u16*)alloc(288 * 128 * 2);
  u16* bnc = (u16*)alloc(128 * 2);
  u16* Wnoc = (u16*)alloc(128 * 32 * 2);
  u16* bnoc = (u16*)alloc(32 * 2);
  u16* Weoc = (u16*)alloc(128 * 32 * 2);
  u16* beoc = (u16*)alloc(32 * 2);
  int* dflag = (int*)alloc(4);
  u16* AGG = Xs;  // overlay: Xs (bf16, 6.4MB) dead after edge stage; AGG consumed
                  // by node_update before next iter's node_proj rewrites Xs

  detect_dtype<<<1, 64, 0, stream>>>(nf_r, dflag);
  // CSR build first (gathers depend on eid)
  hipMemsetAsync(cursor, 0, (size_t)GN * 4, stream);
  hist_kernel<<<1563, 256, 0, stream>>>(dst, cursor, GE);
  scan_kernel<<<1, 256, 0, stream>>>(cursor, rowptr, GN);
  fill_kernel<<<1563, 256, 0, stream>>>(dst, cursor, eid, GE);

  convert_kernel<<<784, 256, 0, stream>>>(nf_r, nfc, (long)GN * 32, dflag);
  gather_ef<<<6250, 256, 0, stream>>>(ef_r, eid, efc, dflag);
  gather_meta<<<1563, 256, 0, stream>>>(src, dst, eid, srcs, dsts, GE);
  convert_kernel<<<240, 256, 0, stream>>>(d_in[4], Wec, 480 * 128, dflag);
  convert_kernel<<<1, 128, 0, stream>>>(d_in[5], bec, 128, dflag);
  convert_kernel<<<2, 256, 0, stream>>>(d_in[6], Wac, 480, dflag);
  convert_kernel<<<1, 64, 0, stream>>>(d_in[7], bac, 1, dflag);
  convert_kernel<<<144, 256, 0, stream>>>(d_in[8], Wnc, 288 * 128, dflag);
  convert_kernel<<<1, 128, 0, stream>>>(d_in[9], bnc, 128, dflag);
  convert_kernel<<<16, 256, 0, stream>>>(d_in[10], Wnoc, 128 * 32, dflag);
  convert_kernel<<<1, 64, 0, stream>>>(d_in[11], bnoc, 32, dflag);
  convert_kernel<<<16, 256, 0, stream>>>(d_in[12], Weoc, 128 * 32, dflag);
  convert_kernel<<<1, 64, 0, stream>>>(d_in[13], beoc, 32, dflag);
  prep_weights<<<128, 256, 0, stream>>>(Wec, Wnc, Wnoc, Weoc, WeT, WnpT, WnuT, WoN, WoE);

  for (int iter = 0; iter < 3; ++iter) {
    int kc0 = (iter == 0) ? 4 : 0;
    dim3 npgrid(NODE_BLKS, 2);
    node_proj<<<npgrid, 256, 0, stream>>>(HNF, nfc, WnpT, Wac, Xs, Xd, as_, ad_, kc0, GN);
    edge_fused<<<EDGE_BLKS, 256, 0, stream>>>(HEF, efc, WeT, Wac, bec, bac, srcs, dsts,
                                              Xs, Xd, as_, ad_, logit, kc0);
    aggregate<<<(GN + 3) / 4, 256, 0, stream>>>(rowptr, logit, HEF, AGG, GN);
    node_update<<<NODE_BLKS, 256, 0, stream>>>(HNF, nfc, AGG, WnuT, bnc, kc0, GN);
  }

  float* out_nf = (float*)d_out;
  float* out_ef = (float*)d_out + (size_t)GN * 32;
  head_kernel<<<NODE_BLKS, 256, 0, stream>>>(HNF, WoN, bnoc, out_nf, GN, nullptr);
  head_kernel<<<EDGE_BLKS, 256, 0, stream>>>(HEF, WoE, beoc, out_ef, GE, eid);
}

// Round 2
// 641.735 us; speedup vs baseline: 1.5024x; 1.0922x over previous
//
#include <hip/hip_runtime.h>

// IJGNN attention-MPNN, 3 iterations. fp32 in/out, bf16 internal.
// Edges processed in dst-sorted (CSR) order; edge head scatters back via eid.
// This rev: edge_fused retiled to 64-edge blocks (acc 2x4 -> 32 VGPR, LDS 17KB,
// occupancy up) + 1-deep K-chunk register prefetch; aggregate reads 4 edges/iter
// via dwordx4 (lane = edge-slot x col-group, shfl combine); weight converts fused
// into prep_weights; gather_meta folded into fill_kernel.

#define GN 25000
#define GE 400000
#define NODE_BLKS 196    // ceil(GN/128)
#define EDGE_BLKS 6250   // GE/64 exact (edge_fused tiles)
#define HEAD_EBLKS 3125  // GE/128 exact (head_kernel tiles)

typedef unsigned short u16;
typedef __attribute__((ext_vector_type(8))) short bf16x8;
typedef __attribute__((ext_vector_type(4))) float f32x4;

__device__ inline float b2f(u16 v) {
  union { unsigned int u; float f; } x; x.u = ((unsigned int)v) << 16; return x.f;
}
__device__ inline u16 f2b(float f) {
  union { float f; unsigned int u; } x; x.f = f;
  unsigned int u = x.u;
  u += 0x7fffu + ((u >> 16) & 1u);
  return (u16)(u >> 16);
}

// ---------------- dtype probe + convert ----------------
__global__ void detect_dtype(const void* nf, int* flag) {
  if (blockIdx.x == 0 && threadIdx.x == 0) {
    const u16* p = (const u16*)nf;
    int cnt = 0;
    for (int i = 0; i < 512; i += 2) {
      int e = (p[i] >> 7) & 0xFF;
      if (e >= 0x70 && e <= 0x85) cnt++;
    }
    *flag = (cnt < 128) ? 1 : 0;
  }
}

__global__ void convert_kernel(const void* src, u16* dst, long n, const int* flag) {
  int f32 = *flag;
  long i = (long)blockIdx.x * blockDim.x + threadIdx.x;
  long stride = (long)gridDim.x * blockDim.x;
  for (; i < n; i += stride)
    dst[i] = f32 ? f2b(((const float*)src)[i]) : ((const u16*)src)[i];
}

// gather ef rows into dst-sorted order (+convert)
__global__ void gather_ef(const void* ef, const int* eid, u16* efc, const int* flag) {
  int f32 = *flag;
  long idx = (long)blockIdx.x * blockDim.x + threadIdx.x;
  long stride = (long)gridDim.x * blockDim.x;
  long ntot = (long)GE * 32;
  for (; idx < ntot; idx += stride) {
    long j = idx >> 5;
    int c = (int)(idx & 31);
    long e = eid[j];
    efc[idx] = f32 ? f2b(((const float*)ef)[e * 32 + c]) : ((const u16*)ef)[e * 32 + c];
  }
}

// ---------------- weight prep: convert (raw f32/bf16) + transpose, one launch ----------------
__global__ void prep_weights(const void* We, const void* Wn, const void* Wa,
                             const void* Won, const void* Woe,
                             const void* be, const void* ba, const void* bn,
                             const void* bno, const void* beo,
                             u16* WeT, u16* WnpT, u16* WnuT, u16* WoN, u16* WoE,
                             u16* Wac, u16* bec, u16* bac, u16* bnc, u16* bnoc, u16* beoc,
                             const int* flag) {
  int f32 = *flag;
  auto ld = [&](const void* p, long i) -> u16 {
    return f32 ? f2b(((const float*)p)[i]) : ((const u16*)p)[i];
  };
  int tid = blockIdx.x * blockDim.x + threadIdx.x;
  int nt = gridDim.x * blockDim.x;
  for (int i = tid; i < 128 * 160; i += nt) { int n = i / 160, k = i % 160; WeT[i] = ld(We, (long)(320 + k) * 128 + n); }
  for (int i = tid; i < 256 * 160; i += nt) {
    int c = i / 160, k = i % 160;
    WnpT[i] = (c < 128) ? ld(We, (long)k * 128 + c) : ld(We, (long)(160 + k) * 128 + (c - 128));
  }
  for (int i = tid; i < 128 * 288; i += nt) { int c = i / 288, k = i % 288; WnuT[i] = ld(Wn, (long)k * 128 + c); }
  for (int i = tid; i < 32 * 128; i += nt) {
    int c = i / 128, k = i % 128;
    WoN[i] = ld(Won, (long)k * 32 + c);
    WoE[i] = ld(Woe, (long)k * 32 + c);
  }
  for (int i = tid; i < 480; i += nt) Wac[i] = ld(Wa, i);
  for (int i = tid; i < 128; i += nt) { bec[i] = ld(be, i); bnc[i] = ld(bn, i); }
  for (int i = tid; i < 32; i += nt) { bnoc[i] = ld(bno, i); beoc[i] = ld(beo, i); }
  if (tid == 0) bac[0] = ld(ba, 0);
}

// ---------------- CSR build ----------------
__global__ void hist_kernel(const int* dst, int* counts, int n) {
  for (int e = blockIdx.x * blockDim.x + threadIdx.x; e < n; e += gridDim.x * blockDim.x)
    atomicAdd(&counts[dst[e]], 1);
}

__global__ __launch_bounds__(256) void scan_kernel(int* cursor, int* rowptr, int n) {
  __shared__ int part[256];
  int t = threadIdx.x;
  int per = (n + 255) / 256;
  int lo = t * per;
  int hi = lo + per; if (hi > n) hi = n;
  if (lo > n) lo = n;
  int s = 0;
  for (int i = lo; i < hi; ++i) s += cursor[i];
  part[t] = s;
  __syncthreads();
  for (int off = 1; off < 256; off <<= 1) {
    int v = (t >= off) ? part[t - off] : 0;
    __syncthreads();
    part[t] += v;
    __syncthreads();
  }
  int run = (t > 0) ? part[t - 1] : 0;
  for (int i = lo; i < hi; ++i) {
    int c = cursor[i];
    cursor[i] = run;
    rowptr[i + 1] = run + c;
    run += c;
  }
  if (t == 0) rowptr[0] = 0;
}

// fill CSR order + gather src/dst meta in the same pass
__global__ void fill_kernel(const int* src, const int* dst, int* cursor, int* eid,
                            int* srcs, int* dsts, int n) {
  for (int e = blockIdx.x * blockDim.x + threadIdx.x; e < n; e += gridDim.x * blockDim.x) {
    int d = dst[e];
    int p = atomicAdd(&cursor[d], 1);
    eid[p] = e;
    srcs[p] = src[e];
    dsts[p] = d;
  }
}

// ---------------- node projections (MFMA): Xs/Xd [N,128] bf16, as/ad [N] fp32 ----------------
__global__ __launch_bounds__(256)
void node_proj(const u16* HNF, const u16* nf, const u16* WnpT, const u16* W_attn,
               u16* Xs, u16* Xd, float* as_, float* ad_, int kc0, int nrows) {
  __shared__ union {
    struct { __align__(16) u16 A[128][40]; __align__(16) u16 B[128][40]; } st;
    u16 C[128][130];  // bf16 transpose buffer (final values; no extra rounding)
  } sm;
  __shared__ float dotbuf[128][2];
  int sel = blockIdx.y, blk = blockIdx.x, tid = threadIdx.x;
  int lane = tid & 63, wv = tid >> 6, wr = wv & 1, wc = wv >> 1;
  const u16* BT = WnpT + sel * 128 * 160;
  u16* OUT = sel ? Xd : Xs;
  float* AOUT = sel ? ad_ : as_;
  const u16* wa = W_attn + sel * 160;
  f32x4 acc[4][4];
  f32x4 zf = {0.f, 0.f, 0.f, 0.f};
  for (int i = 0; i < 4; ++i) for (int j = 0; j < 4; ++j) acc[i][j] = zf;
  float dp = 0.f;
  int arow = tid >> 1, ahalf = (tid & 1) * 16;
  int r0 = blk * 128;
  for (int kc = kc0; kc < 5; ++kc) {
    {
      int r = r0 + arow;
      uint4 v0 = make_uint4(0, 0, 0, 0), v1 = make_uint4(0, 0, 0, 0);
      if (r < nrows) {
        const uint4* p = (kc < 4) ? (const uint4*)(HNF + (size_t)r * 128 + kc * 32 + ahalf)
                                  : (const uint4*)(nf + (size_t)r * 32 + ahalf);
        v0 = p[0]; v1 = p[1];
      }
      *(uint4*)&sm.st.A[arow][ahalf] = v0;
      *(uint4*)&sm.st.A[arow][ahalf + 8] = v1;
    }
    {
      const uint4* p = (const uint4*)(BT + arow * 160 + kc * 32 + ahalf);
      uint4 v0 = p[0], v1 = p[1];
      *(uint4*)&sm.st.B[arow][ahalf] = v0;
      *(uint4*)&sm.st.B[arow][ahalf + 8] = v1;
    }
    __syncthreads();
    {
      float s = 0.f;
      for (int j = 0; j < 16; ++j) s += b2f(sm.st.A[arow][ahalf + j]) * b2f(wa[kc * 32 + ahalf + j]);
      dp += s;
    }
    int q = lane >> 4, l16 = lane & 15;
    bf16x8 af[4], bfr[4];
    for (int i = 0; i < 4; ++i) af[i] = *(const bf16x8*)&sm.st.A[wr * 64 + i * 16 + l16][q * 8];
    for (int j = 0; j < 4; ++j) bfr[j] = *(const bf16x8*)&sm.st.B[wc * 64 + j * 16 + l16][q * 8];
    for (int i = 0; i < 4; ++i)
      for (int j = 0; j < 4; ++j)
        acc[i][j] = __builtin_amdgcn_mfma_f32_16x16x32_bf16(af[i], bfr[j], acc[i][j], 0, 0, 0);
    __syncthreads();
  }
  dotbuf[arow][tid & 1] = dp;
  // scatter acc -> LDS transpose buffer (overlays staging; K-loop is done)
  {
    int q = lane >> 4, l16 = lane & 15;
    for (int i = 0; i < 4; ++i)
      for (int j = 0; j < 4; ++j) {
        int col = wc * 64 + j * 16 + l16;
        for (int rr = 0; rr < 4; ++rr) {
          int row = wr * 64 + i * 16 + q * 4 + rr;
          sm.C[row][col] = f2b(acc[i][j][rr]);
        }
      }
  }
  __syncthreads();
  if (tid < 128) {
    int r = r0 + tid;
    if (r < nrows) AOUT[r] = dotbuf[tid][0] + dotbuf[tid][1];
  }
  // vectorized store: each thread owns one row-half (64 cols = 8x dwordx4)
  {
    int r = tid >> 1, h = (tid & 1) * 64;
    int rg = r0 + r;
    if (rg < nrows) {
      uint4* po = (uint4*)(OUT + (size_t)rg * 128 + h);
      for (int k = 0; k < 8; ++k) {
        unsigned int a0 = *(const unsigned int*)&sm.C[r][h + k * 8];
        unsigned int a1 = *(const unsigned int*)&sm.C[r][h + k * 8 + 2];
        unsigned int a2 = *(const unsigned int*)&sm.C[r][h + k * 8 + 4];
        unsigned int a3 = *(const unsigned int*)&sm.C[r][h + k * 8 + 6];
        po[k] = make_uint4(a0, a1, a2, a3);
      }
    }
  }
}

// ---------------- edge stage: 64-edge tiles, MFMA GEMM + prefetch + fused epilogue ----------------
// Per block: A tile 64x32/chunk, B tile 128x32/chunk, 4 waves each owning a
// 32x64 output. 1-deep register prefetch of next K-chunk hides HBM latency of
// the HEF stream under MFMA. Epilogue: two 64-col passes through f32 LDS
// transpose (no extra rounding), vector gathers of Xs/Xd + vector HEF stores.
__global__ __launch_bounds__(256, 4)
void edge_fused(u16* HEF, const u16* ef, const u16* WeT, const u16* W_attn,
                const u16* b_edge, const u16* b_attn, const int* srcs, const int* dsts,
                const u16* Xs, const u16* Xd, const float* as_, const float* ad_,
                float* logit, int kc0) {
  __shared__ union {
    struct { __align__(16) u16 A[64][40]; __align__(16) u16 B[128][40]; } st;
    float C[64][65];  // stride 65 dwords: bank spread, <=2-way on reads
  } sm;
  __shared__ float dotbuf[64];
  int blk = blockIdx.x, tid = threadIdx.x;
  int lane = tid & 63, wv = tid >> 6, wr = wv & 1, wc = wv >> 1;
  int q = lane >> 4, l16 = lane & 15;
  f32x4 acc[2][4];
  f32x4 zf = {0.f, 0.f, 0.f, 0.f};
  for (int i = 0; i < 2; ++i) for (int j = 0; j < 4; ++j) acc[i][j] = zf;
  float dp[2] = {0.f, 0.f};
  long e0 = (long)blk * 64;
  long ea = e0 + (tid >> 2);
  int qp = (tid & 3) * 8;          // A col offset (u16 units), 16B per thread
  int brow = tid >> 1, bh = (tid & 1) * 16;
  const u16* wa = W_attn + 320;
  uint4 va, vb0, vb1;
  {
    const uint4* pa = (kc0 < 4) ? (const uint4*)(HEF + ea * 128 + kc0 * 32 + qp)
                                : (const uint4*)(ef + ea * 32 + qp);
    va = pa[0];
    const uint4* pb = (const uint4*)(WeT + brow * 160 + kc0 * 32 + bh);
    vb0 = pb[0]; vb1 = pb[1];
  }
  for (int kc = kc0; kc < 5; ++kc) {
    *(uint4*)&sm.st.A[tid >> 2][qp] = va;
    *(uint4*)&sm.st.B[brow][bh] = vb0;
    *(uint4*)&sm.st.B[brow][bh + 8] = vb1;
    __syncthreads();
    if (kc < 4) {  // prefetch next chunk; latency overlaps frag reads + MFMA
      int kn = kc + 1;
      const uint4* pa = (kn < 4) ? (const uint4*)(HEF + ea * 128 + kn * 32 + qp)
                                 : (const uint4*)(ef + ea * 32 + qp);
      va = pa[0];
      const uint4* pb = (const uint4*)(WeT + brow * 160 + kn * 32 + bh);
      vb0 = pb[0]; vb1 = pb[1];
    }
    bf16x8 af[2], bfr[4];
    for (int i = 0; i < 2; ++i) af[i] = *(const bf16x8*)&sm.st.A[wr * 32 + i * 16 + l16][q * 8];
    for (int j = 0; j < 4; ++j) bfr[j] = *(const bf16x8*)&sm.st.B[wc * 64 + j * 16 + l16][q * 8];
    if (wc == 0) {
      bf16x8 wv8 = *(const bf16x8*)&wa[kc * 32 + q * 8];
      float wf[8];
      for (int j = 0; j < 8; ++j) wf[j] = b2f((u16)wv8[j]);
      for (int i = 0; i < 2; ++i)
        for (int j = 0; j < 8; ++j) dp[i] += b2f((u16)af[i][j]) * wf[j];
    }
    for (int i = 0; i < 2; ++i)
      for (int j = 0; j < 4; ++j)
        acc[i][j] = __builtin_amdgcn_mfma_f32_16x16x32_bf16(af[i], bfr[j], acc[i][j], 0, 0, 0);
    __syncthreads();
  }
  if (wc == 0) {
    for (int i = 0; i < 2; ++i) {
      dp[i] += __shfl_xor(dp[i], 16);
      dp[i] += __shfl_xor(dp[i], 32);
    }
    if (q == 0)
      for (int i = 0; i < 2; ++i) dotbuf[wr * 32 + i * 16 + l16] = dp[i];
  }
  int r = tid >> 2, qh = tid & 3;  // each thread: one edge row, 16 cols/pass
  long e = e0 + r;
  int s = srcs[e], d = dsts[e];
  for (int p = 0; p < 2; ++p) {
    int cb = p * 64 + qh * 16;
    // issue vector gathers early: latency hides under LDS scatter + barrier
    const uint4* ps = (const uint4*)(Xs + (size_t)s * 128 + cb);
    const uint4* pd = (const uint4*)(Xd + (size_t)d * 128 + cb);
    uint4 gs0 = ps[0], gs1 = ps[1], gd0 = pd[0], gd1 = pd[1];
    if (p) __syncthreads();  // protect C from previous pass's readers
    if (wc == p) {           // this wave pair's acc covers cols [p*64, p*64+64)
      for (int i = 0; i < 2; ++i)
        for (int j = 0; j < 4; ++j) {
          int col = j * 16 + l16;
          float bb = b2f(b_edge[p * 64 + col]);
          for (int rr = 0; rr < 4; ++rr)
            sm.C[wr * 32 + i * 16 + q * 4 + rr][col] = acc[i][j][rr] + bb;
        }
    }
    __syncthreads();
    if (p == 0 && tid < 64) {
      long ee = e0 + tid;
      logit[ee] = dotbuf[tid] + as_[srcs[ee]] + ad_[dsts[ee]] + b2f(b_attn[0]);
    }
    unsigned int us[8], ud[8];
    *(uint4*)&us[0] = gs0; *(uint4*)&us[4] = gs1;
    *(uint4*)&ud[0] = gd0; *(uint4*)&ud[4] = gd1;
    unsigned int ov[8];
    for (int w = 0; w < 8; ++w) {
      float c0 = sm.C[r][qh * 16 + 2 * w];
      float c1 = sm.C[r][qh * 16 + 2 * w + 1];
      float v0 = c0 + b2f((u16)(us[w] & 0xffffu)) + b2f((u16)(ud[w] & 0xffffu));
      float v1 = c1 + b2f((u16)(us[w] >> 16)) + b2f((u16)(ud[w] >> 16));
      ov[w] = (unsigned int)f2b(fmaxf(v0, 0.f)) | ((unsigned int)f2b(fmaxf(v1, 0.f)) << 16);
    }
    uint4* po = (uint4*)(HEF + e * 128 + cb);
    po[0] = *(uint4*)&ov[0];
    po[1] = *(uint4*)&ov[4];
  }
}

// ---------------- per-dst softmax + aggregation ----------------
// 1 wave per dst row; 4 edges/iteration: lane = (edge-slot sub, col-group cl),
// dwordx4 M reads (16B/lane), shfl_xor(16,32) folds the 4 edge-slots.
__global__ __launch_bounds__(256)
void aggregate(const int* rowptr, const float* logit, const u16* M, u16* AGG, int nrows) {
  int gw = (blockIdx.x * blockDim.x + threadIdx.x) >> 6;
  int lane = threadIdx.x & 63;
  if (gw >= nrows) return;
  int beg = rowptr[gw], end = rowptr[gw + 1];
  int sub = lane >> 4, cl = lane & 15;
  float mx = -1e30f;
  for (int j = beg + lane; j < end; j += 64) mx = fmaxf(mx, logit[j]);
  for (int off = 32; off > 0; off >>= 1) mx = fmaxf(mx, __shfl_xor(mx, off));
  float acc[8] = {0.f, 0.f, 0.f, 0.f, 0.f, 0.f, 0.f, 0.f};
  float denom = 0.f;
  for (int j0 = beg; j0 < end; j0 += 4) {
    int j = j0 + sub;
    float w = 0.f;
    uint4 mv = make_uint4(0, 0, 0, 0);
    if (j < end) {
      w = __expf(logit[j] - mx);
      mv = *(const uint4*)(M + (size_t)j * 128 + cl * 8);
    }
    denom += w;
    const unsigned int* mw = (const unsigned int*)&mv;
    for (int t = 0; t < 4; ++t) {
      acc[2 * t]     += w * b2f((u16)(mw[t] & 0xffffu));
      acc[2 * t + 1] += w * b2f((u16)(mw[t] >> 16));
    }
  }
  denom += __shfl_xor(denom, 16);
  denom += __shfl_xor(denom, 32);
  for (int t = 0; t < 8; ++t) {
    acc[t] += __shfl_xor(acc[t], 16);
    acc[t] += __shfl_xor(acc[t], 32);
  }
  float inv = 1.0f / fmaxf(denom, 1e-16f);
  if (sub == 0) {
    unsigned int ov[4];
    for (int t = 0; t < 4; ++t)
      ov[t] = (unsigned int)f2b(acc[2 * t] * inv) | ((unsigned int)f2b(acc[2 * t + 1] * inv) << 16);
    *(uint4*)(AGG + (size_t)gw * 128 + cl * 8) = *(uint4*)ov;
  }
}

// ---------------- node update (MFMA, in-place HNF) ----------------
__global__ __launch_bounds__(256)
void node_update(u16* HNF, const u16* nf, const u16* AGG, const u16* WnuT,
                 const u16* b_node, int kc0, int nrows) {
  __shared__ union {
    struct { __align__(16) u16 A[128][40]; __align__(16) u16 B[128][40]; } st;
    u16 C[128][130];
  } sm;
  int blk = blockIdx.x, tid = threadIdx.x;
  int lane = tid & 63, wv = tid >> 6, wr = wv & 1, wc = wv >> 1;
  f32x4 acc[4][4];
  f32x4 zf = {0.f, 0.f, 0.f, 0.f};
  for (int i = 0; i < 4; ++i) for (int j = 0; j < 4; ++j) acc[i][j] = zf;
  int arow = tid >> 1, ahalf = (tid & 1) * 16;
  int r0 = blk * 128;
  for (int kc = kc0; kc < 9; ++kc) {
    {
      int r = r0 + arow;
      uint4 v0 = make_uint4(0, 0, 0, 0), v1 = make_uint4(0, 0, 0, 0);
      if (r < nrows) {
        const u16* p;
        if (kc < 4) p = HNF + (size_t)r * 128 + kc * 32 + ahalf;
        else if (kc == 4) p = nf + (size_t)r * 32 + ahalf;
        else p = AGG + (size_t)r * 128 + (kc - 5) * 32 + ahalf;
        v0 = ((const uint4*)p)[0];
        v1 = ((const uint4*)p)[1];
      }
      *(uint4*)&sm.st.A[arow][ahalf] = v0;
      *(uint4*)&sm.st.A[arow][ahalf + 8] = v1;
    }
    {
      const uint4* p = (const uint4*)(WnuT + arow * 288 + kc * 32 + ahalf);
      uint4 v0 = p[0], v1 = p[1];
      *(uint4*)&sm.st.B[arow][ahalf] = v0;
      *(uint4*)&sm.st.B[arow][ahalf + 8] = v1;
    }
    __syncthreads();
    int q = lane >> 4, l16 = lane & 15;
    bf16x8 af[4], bfr[4];
    for (int i = 0; i < 4; ++i) af[i] = *(const bf16x8*)&sm.st.A[wr * 64 + i * 16 + l16][q * 8];
    for (int j = 0; j < 4; ++j) bfr[j] = *(const bf16x8*)&sm.st.B[wc * 64 + j * 16 + l16][q * 8];
    for (int i = 0; i < 4; ++i)
      for (int j = 0; j < 4; ++j)
        acc[i][j] = __builtin_amdgcn_mfma_f32_16x16x32_bf16(af[i], bfr[j], acc[i][j], 0, 0, 0);
    __syncthreads();
  }
  int q = lane >> 4, l16 = lane & 15;
  for (int i = 0; i < 4; ++i)
    for (int j = 0; j < 4; ++j) {
      int col = wc * 64 + j * 16 + l16;
      float bb = b2f(b_node[col]);
      for (int rr = 0; rr < 4; ++rr) {
        int row = wr * 64 + i * 16 + q * 4 + rr;
        sm.C[row][col] = f2b(fmaxf(acc[i][j][rr] + bb, 0.f));
      }
    }
  __syncthreads();
  {
    int r = tid >> 1, h = (tid & 1) * 64;
    int rg = r0 + r;
    if (rg < nrows) {
      uint4* po = (uint4*)(HNF + (size_t)rg * 128 + h);
      for (int k = 0; k < 8; ++k) {
        unsigned int a0 = *(const unsigned int*)&sm.C[r][h + k * 8];
        unsigned int a1 = *(const unsigned int*)&sm.C[r][h + k * 8 + 2];
        unsigned int a2 = *(const unsigned int*)&sm.C[r][h + k * 8 + 4];
        unsigned int a3 = *(const unsigned int*)&sm.C[r][h + k * 8 + 6];
        po[k] = make_uint4(a0, a1, a2, a3);
      }
    }
  }
}

// ---------------- output heads (MFMA, fp32 output, optional row remap) ----------------
__global__ __launch_bounds__(256)
void head_kernel(const u16* IN, const u16* WT, const u16* bias, float* OUT, long R,
                 const int* remap) {
  __shared__ __align__(16) u16 Asm[128][40];
  __shared__ __align__(16) u16 Bsm[32][40];
  int blk = blockIdx.x, tid = threadIdx.x;
  int lane = tid & 63, wv = tid >> 6;
  f32x4 acc[2][2];
  f32x4 zf = {0.f, 0.f, 0.f, 0.f};
  for (int i = 0; i < 2; ++i) for (int j = 0; j < 2; ++j) acc[i][j] = zf;
  int arow = tid >> 1, ahalf = (tid & 1) * 16;
  long r0 = (long)blk * 128;
  for (int kc = 0; kc < 4; ++kc) {
    {
      long r = r0 + arow;
      uint4 v0 = make_uint4(0, 0, 0, 0), v1 = make_uint4(0, 0, 0, 0);
      if (r < R) {
        const uint4* p = (const uint4*)(IN + r * 128 + kc * 32 + ahalf);
        v0 = p[0]; v1 = p[1];
      }
      *(uint4*)&Asm[arow][ahalf] = v0;
      *(uint4*)&Asm[arow][ahalf + 8] = v1;
    }
    if (tid < 64) {
      const uint4* p = (const uint4*)(WT + arow * 128 + kc * 32 + ahalf);
      uint4 v0 = p[0], v1 = p[1];
      *(uint4*)&Bsm[arow][ahalf] = v0;
      *(uint4*)&Bsm[arow][ahalf + 8] = v1;
    }
    __syncthreads();
    int q = lane >> 4, l16 = lane & 15;
    bf16x8 af[2], bfr[2];
    for (int i = 0; i < 2; ++i) af[i] = *(const bf16x8*)&Asm[wv * 32 + i * 16 + l16][q * 8];
    for (int j = 0; j < 2; ++j) bfr[j] = *(const bf16x8*)&Bsm[j * 16 + l16][q * 8];
    for (int i = 0; i < 2; ++i)
      for (int j = 0; j < 2; ++j)
        acc[i][j] = __builtin_amdgcn_mfma_f32_16x16x32_bf16(af[i], bfr[j], acc[i][j], 0, 0, 0);
    __syncthreads();
  }
  int q = lane >> 4, l16 = lane & 15;
  for (int i = 0; i < 2; ++i)
    for (int rr = 0; rr < 4; ++rr) {
      long r = r0 + wv * 32 + i * 16 + q * 4 + rr;
      if (r < R) {
        long ro = remap ? (long)remap[r] : r;
        for (int j = 0; j < 2; ++j) {
          int col = j * 16 + l16;
          OUT[ro * 32 + col] = acc[i][j][rr] + b2f(bias[col]);
        }
      }
    }
}

extern "C" void kernel_launch(void* const* d_in, const int* in_sizes, int n_in,
                              void* d_out, int out_size, void* d_ws, size_t ws_size,
                              hipStream_t stream) {
  const size_t REQUIRED = 160000000;
  if (ws_size < REQUIRED) return;

  const void* nf_r = d_in[0];
  const void* ef_r = d_in[1];
  const int* src = (const int*)d_in[2];
  const int* dst = (const int*)d_in[3];

  char* ws = (char*)d_ws;
  auto alloc = [&](size_t bytes) {
    char* p = ws;
    ws += (bytes + 255) & ~(size_t)255;
    return p;
  };
  u16* HEF = (u16*)alloc((size_t)GE * 128 * 2);
  u16* HNF = (u16*)alloc((size_t)GN * 128 * 2);
  u16* Xs = (u16*)alloc((size_t)GN * 128 * 2);
  u16* Xd = (u16*)alloc((size_t)GN * 128 * 2);
  float* as_ = (float*)alloc((size_t)GN * 4);
  float* ad_ = (float*)alloc((size_t)GN * 4);
  float* logit = (float*)alloc((size_t)GE * 4);
  int* rowptr = (int*)alloc((size_t)(GN + 1) * 4);
  int* cursor = (int*)alloc((size_t)GN * 4);
  int* eid = (int*)alloc((size_t)GE * 4);
  int* srcs = (int*)alloc((size_t)GE * 4);
  int* dsts = (int*)alloc((size_t)GE * 4);
  u16* WeT = (u16*)alloc(128 * 160 * 2);
  u16* WnpT = (u16*)alloc(256 * 160 * 2);
  u16* WnuT = (u16*)alloc(128 * 288 * 2);
  u16* WoN = (u16*)alloc(32 * 128 * 2);
  u16* WoE = (u16*)alloc(32 * 128 * 2);
  u16* nfc = (u16*)alloc((size_t)GN * 32 * 2);
  u16* efc = (u16*)alloc((size_t)GE * 32 * 2);
  u16* bec = (u16*)alloc(128 * 2);
  u16* Wac = (u16*)alloc(480 * 2);
  u16* bac = (u16*)alloc(2);
  u16* bnc = (u16*)alloc(128 * 2);
  u16* bnoc = (u16*)alloc(32 * 2);
  u16* beoc = (u16*)alloc(32 * 2);
  int* dflag = (int*)alloc(4);
  u16* AGG = Xs;  // overlay: Xs (bf16, 6.4MB) dead after edge stage; AGG consumed
                  // by node_update before next iter's node_proj rewrites Xs

  detect_dtype<<<1, 64, 0, stream>>>(nf_r, dflag);
  // CSR build first (gathers depend on eid)
  hipMemsetAsync(cursor, 0, (size_t)GN * 4, stream);
  hist_kernel<<<1563, 256, 0, stream>>>(dst, cursor, GE);
  scan_kernel<<<1, 256, 0, stream>>>(cursor, rowptr, GN);
  fill_kernel<<<1563, 256, 0, stream>>>(src, dst, cursor, eid, srcs, dsts, GE);

  convert_kernel<<<784, 256, 0, stream>>>(nf_r, nfc, (long)GN * 32, dflag);
  gather_ef<<<6250, 256, 0, stream>>>(ef_r, eid, efc, dflag);
  prep_weights<<<128, 256, 0, stream>>>(d_in[4], d_in[8], d_in[6], d_in[10], d_in[12],
                                        d_in[5], d_in[7], d_in[9], d_in[11], d_in[13],
                                        WeT, WnpT, WnuT, WoN, WoE,
                                        Wac, bec, bac, bnc, bnoc, beoc, dflag);

  for (int iter = 0; iter < 3; ++iter) {
    int kc0 = (iter == 0) ? 4 : 0;
    dim3 npgrid(NODE_BLKS, 2);
    node_proj<<<npgrid, 256, 0, stream>>>(HNF, nfc, WnpT, Wac, Xs, Xd, as_, ad_, kc0, GN);
    edge_fused<<<EDGE_BLKS, 256, 0, stream>>>(HEF, efc, WeT, Wac, bec, bac, srcs, dsts,
                                              Xs, Xd, as_, ad_, logit, kc0);
    aggregate<<<(GN + 3) / 4, 256, 0, stream>>>(rowptr, logit, HEF, AGG, GN);
    node_update<<<NODE_BLKS, 256, 0, stream>>>(HNF, nfc, AGG, WnuT, bnc, kc0, GN);
  }

  float* out_nf = (float*)d_out;
  float* out_ef = (float*)d_out + (size_t)GN * 32;
  head_kernel<<<NODE_BLKS, 256, 0, stream>>>(HNF, WoN, bnoc, out_nf, GN, nullptr);
  head_kernel<<<HEAD_EBLKS, 256, 0, stream>>>(HEF, WoE, beoc, out_ef, GE, eid);
}